// Round 16
// baseline (760.658 us; speedup 1.0000x reference)
//
#include <hip/hip_runtime.h>
#include <math.h>

// Problem constants (fixed by setup_inputs)
#define TLEN   8192
#define CCH    512
#define NBATCH 4
#define GUARD_B 8
#define GUARD_T 16
#define XROWS  (TLEN + GUARD_B + GUARD_T)   // 8216 guarded rows per batch

typedef __attribute__((ext_vector_type(8))) short short8;
typedef __attribute__((ext_vector_type(4))) float f32x4;

struct Filt { float f[12]; };

#define MFMA16(a, b, c) __builtin_amdgcn_mfma_f32_16x16x32_bf16(a, b, c, 0, 0, 0)

// ---------------------------------------------------------------------------
// device helpers
// ---------------------------------------------------------------------------
__device__ __forceinline__ unsigned short f2bf(float f) {
  unsigned u = __float_as_uint(f);
  unsigned r = (u + 0x7fffu + ((u >> 16) & 1u)) >> 16;   // RNE
  return (unsigned short)r;
}

__device__ __forceinline__ float bf2f(unsigned short u) {
  return __uint_as_float((unsigned)u << 16);
}

__device__ __forceinline__ float fast_sin(float x) {
  float r = x * 0.15915494309189535f;   // radians -> revolutions
  r -= floorf(r);
  return __builtin_amdgcn_sinf(r);
}

__device__ __forceinline__ float snake1(float u, float a, float rcp) {
  float s = fast_sin(a * u);
  return fmaf(rcp * s, s, u);   // u + (1/a)*sin^2(a*u)
}

// global (per-lane addr) -> LDS (wave-uniform base; HW adds lane*16), 16B/lane
__device__ __forceinline__ void gload16(const void* g, void* l) {
  __builtin_amdgcn_global_load_lds(
      (const __attribute__((address_space(1))) unsigned int*)g,
      (__attribute__((address_space(3))) unsigned int*)l, 16, 0, 0);
}

// ---------------------------------------------------------------------------
// weight-norm sum-of-squares, stage 1: partial[(c*512+co)*24 + jc]
// ---------------------------------------------------------------------------
__global__ __launch_bounds__(256)
void normp_k(const float* __restrict__ v1, const float* __restrict__ v2,
             float* __restrict__ part) {
  __shared__ float red[256];
  const int c  = blockIdx.x;
  const int cc = blockIdx.y;
  const int jc = blockIdx.z;
  const int col = threadIdx.x & 63;
  const int js  = threadIdx.x >> 6;
  const int co = cc * 64 + col;
  const float* v = (c < 3) ? v1 + (size_t)c * 3 * CCH * CCH
                           : v2 + (size_t)(c - 3) * 3 * CCH * CCH;
  const int j0 = jc * 64 + js * 16;
  float s = 0.f;
  #pragma unroll
  for (int jj = 0; jj < 16; ++jj) {
    float w = v[(size_t)(j0 + jj) * CCH + co];
    s = fmaf(w, w, s);
  }
  red[threadIdx.x] = s;
  __syncthreads();
  if (threadIdx.x < 64) {
    float t = red[threadIdx.x] + red[threadIdx.x + 64] +
              red[threadIdx.x + 128] + red[threadIdx.x + 192];
    part[(size_t)(c * CCH + co) * 24 + jc] = t;
  }
}

// stage 2: scl[c*512+co] = g / sqrt(sum of 24 partials)
__global__ __launch_bounds__(256)
void fin_k(const float* __restrict__ part, const float* __restrict__ g1,
           const float* __restrict__ g2, float* __restrict__ scl) {
  const int i = blockIdx.x * 256 + threadIdx.x;   // 0..3071
  const int c = i >> 9, co = i & 511;
  float s = 0.f;
  #pragma unroll
  for (int jc = 0; jc < 24; ++jc) s += part[(size_t)i * 24 + jc];
  const float g = (c < 3) ? g1[c * CCH + co] : g2[(c - 3) * CCH + co];
  scl[i] = g / sqrtf(s);
}

// ---------------------------------------------------------------------------
// zero the guard rows of the PACKED bf16 activation buffer.
// xbuf layout: [b][cb32(16)][XROWS][32].  96 blocks x 512 thr.
// ---------------------------------------------------------------------------
__global__ __launch_bounds__(512)
void zguard_k(unsigned short* __restrict__ xb) {
  const int b = blockIdx.x / 24;
  const int g = blockIdx.x % 24;
  const int row = (g < 8) ? g : (TLEN + g);          // 0..7 and 8200..8215
  const int cb = threadIdx.x >> 5;
  const int ci = threadIdx.x & 31;
  xb[(((size_t)(b * 16 + cb) * XROWS) + row) * 32 + ci] = 0;
}

// ---------------------------------------------------------------------------
// pack weights into MFMA B-fragment order (weight-norm scale folded in).
// Layout: wp[c][s = cb32*3+tap (48)][chunk(32)][512]
//   co = chunk*16 + (lane&15)
//   ci = cb32*32 + (lane>>4)*8 + jj
// ---------------------------------------------------------------------------
__global__ __launch_bounds__(256)
void wprep_k(const float* __restrict__ v1, const float* __restrict__ v2,
             const float* __restrict__ scl, unsigned short* __restrict__ wp) {
  const int gtid = blockIdx.x * 256 + threadIdx.x;
  const int lane = gtid & 63;
  const int gw = gtid >> 6;            // 0..9215
  const int c  = gw / 1536;
  const int r  = gw - c * 1536;
  const int s  = r >> 5;               // 0..47
  const int chunk = r & 31;
  const int tap = s % 3, cb32 = s / 3;
  const int co  = chunk * 16 + (lane & 15);
  const int ci0 = cb32 * 32 + (lane >> 4) * 8;
  const float* v = (c < 3) ? v1 + (size_t)c * 3 * CCH * CCH
                           : v2 + (size_t)(c - 3) * 3 * CCH * CCH;
  const float sc = scl[c * CCH + co];
  unsigned short o[8];
  #pragma unroll
  for (int jj = 0; jj < 8; ++jj) {
    float w = v[((size_t)tap * CCH + ci0 + jj) * CCH + co] * sc;
    o[jj] = f2bf(w);
  }
  *reinterpret_cast<short8*>(wp + (size_t)gw * 512 + lane * 8) =
      *reinterpret_cast<const short8*>(o);
}

// ---------------------------------------------------------------------------
// fused Activation1d: 2x upsample -> snake -> 2x downsample, strip-tiled.
// INBF: input is bf16 (flat B,T,C), else fp32.
// Output: PACKED guarded buffer [b][cb32(16)][XROWS][32].
// ---------------------------------------------------------------------------
template<int INBF>
__global__ __launch_bounds__(256)
void act_k(const void* __restrict__ xin, unsigned short* __restrict__ y,
           const float* __restrict__ la, Filt F) {
  const int idx = blockIdx.x * 256 + threadIdx.x;    // 4 * 2048 * 128 threads
  const int c  = (idx & 127) << 2;
  const int ts = (idx >> 7) & 2047;                  // strip index (t0 = 4*ts)
  const int b  = idx >> 18;
  const int t0 = ts * 4;

  auto ldrow = [&](int row) -> f32x4 {
    if constexpr (INBF) {
      const unsigned short* p =
          (const unsigned short*)xin + ((size_t)b * TLEN + row) * CCH + c;
      ushort4 u = *reinterpret_cast<const ushort4*>(p);
      f32x4 r;
      r[0] = bf2f(u.x); r[1] = bf2f(u.y); r[2] = bf2f(u.z); r[3] = bf2f(u.w);
      return r;
    } else {
      const float* p = (const float*)xin + ((size_t)b * TLEN + row) * CCH + c;
      return *reinterpret_cast<const f32x4*>(p);
    }
  };

  float av[4], rv[4];
  #pragma unroll
  for (int ch = 0; ch < 4; ++ch) {
    av[ch] = expf(la[c + ch]);
    rv[ch] = 1.f / (av[ch] + 1e-9f);
  }

  float acc[4][4];   // [tt][ch]

  if (ts >= 2 && ts <= 2045) {
    f32x4 xw[14];
    #pragma unroll
    for (int j = 0; j < 14; ++j) xw[j] = ldrow(t0 - 5 + j);

    #pragma unroll
    for (int ch = 0; ch < 4; ++ch) {
      float s[18];
      #pragma unroll
      for (int mi = 0; mi < 18; ++mi) {
        float u = 0.f;
        if (mi & 1) {
          const int base = (mi - 5) / 2 + 2;
          #pragma unroll
          for (int r = 0; r < 6; ++r) u = fmaf(F.f[2*r], xw[base + r][ch], u);
        } else {
          const int base = (mi - 6) / 2 + 3;
          #pragma unroll
          for (int r = 0; r < 6; ++r) u = fmaf(F.f[2*r+1], xw[base + r][ch], u);
        }
        u *= 2.f;
        s[mi] = snake1(u, av[ch], rv[ch]);
      }
      #pragma unroll
      for (int tt = 0; tt < 4; ++tt) {
        float a = 0.f;
        #pragma unroll
        for (int k = 0; k < 12; ++k) a = fmaf(F.f[k], s[2*tt + k], a);
        acc[tt][ch] = a;
      }
    }
  } else {
    #pragma unroll
    for (int tt = 0; tt < 4; ++tt) {
      const int t = t0 + tt;
      float a0=0.f, a1=0.f, a2=0.f, a3=0.f;
      for (int k = 0; k < 12; ++k) {
        int m  = 2*t + k - 5;
        int mc = m < 0 ? 0 : (m > 2*TLEN - 1 ? 2*TLEN - 1 : m);
        int tp = mc >> 1;
        int odd = mc & 1;
        float u0=0.f,u1=0.f,u2=0.f,u3=0.f;
        #pragma unroll
        for (int r = 0; r < 6; ++r) {
          int i  = odd ? (tp + r - 2) : (tp + r - 3);
          int ic = i < 0 ? 0 : (i > TLEN - 1 ? TLEN - 1 : i);
          float tap = odd ? F.f[2*r+1] : F.f[2*r];
          f32x4 xv = ldrow(ic);
          u0 = fmaf(tap, xv[0], u0); u1 = fmaf(tap, xv[1], u1);
          u2 = fmaf(tap, xv[2], u2); u3 = fmaf(tap, xv[3], u3);
        }
        u0 *= 2.f; u1 *= 2.f; u2 *= 2.f; u3 *= 2.f;
        const float fk = F.f[k];
        a0 = fmaf(fk, snake1(u0,av[0],rv[0]), a0);
        a1 = fmaf(fk, snake1(u1,av[1],rv[1]), a1);
        a2 = fmaf(fk, snake1(u2,av[2],rv[2]), a2);
        a3 = fmaf(fk, snake1(u3,av[3],rv[3]), a3);
      }
      acc[tt][0]=a0; acc[tt][1]=a1; acc[tt][2]=a2; acc[tt][3]=a3;
    }
  }

  // packed write: bucket cb = c>>5, within-row offset c&31
  const int cb = c >> 5;
  const int cw = c & 31;
  unsigned short* yb =
      y + (((size_t)(b * 16 + cb) * XROWS) + GUARD_B + t0) * 32 + cw;
  #pragma unroll
  for (int tt = 0; tt < 4; ++tt) {
    ushort4 o;
    o.x = f2bf(acc[tt][0]); o.y = f2bf(acc[tt][1]);
    o.z = f2bf(acc[tt][2]); o.w = f2bf(acc[tt][3]);
    *reinterpret_cast<ushort4*>(yb + (size_t)tt * 32) = o;
  }
}

// ---------------------------------------------------------------------------
// MFMA conv — FULL-N block (BM=128 x BN=512): each A-panel is fetched by
// EXACTLY ONE block -> A HBM fetch = 33.5MB by construction (was 88MB from
// coT-pair L2 thrash). B becomes the streamed operand: 32KB/step dbuf LDS,
// entire 1.5MB/block (L2-served per XCD). 8 waves = 2M x 4N, 64x128/wave.
// A: [2][144x32] per-cb32 bucket slot (halo covers all 3 taps, DIL<=5).
// K order: cb32 (16) x tap (3) = 48 steps of 32-ci; 32 MFMA/step/wave.
// Sync: proven 2-phase __syncthreads (9 experiments: sync style irrelevant).
// MODE: 0 conv1->bf16; 1 res fp32->bf16; 2 res bf16->bf16; 3 res bf16->fp32.
// ---------------------------------------------------------------------------
template<int DIL, int MODE>
__global__ __launch_bounds__(512)
void convm_k(const unsigned short* __restrict__ xb,
             const unsigned short* __restrict__ wp,
             const float* __restrict__ bia,
             const float* __restrict__ resf,
             const unsigned short* __restrict__ resb,
             float* __restrict__ outf,
             unsigned short* __restrict__ outb) {
  __shared__ unsigned short Abuf[2][144 * 32];   // 9KB x2
  __shared__ unsigned short Bbuf[2][32 * 512];   // 32KB x2  (82KB total)

  const int tid  = threadIdx.x;
  const int lane = tid & 63;
  const int wid  = tid >> 6;            // 0..7
  const int wm   = wid >> 2;            // 0..1  row half (64 rows each)
  const int wn   = wid & 3;             // 0..3  col quarter (128 cols each)

  const int tb = blockIdx.x;            // 0..255
  const int b  = tb >> 6;
  const int t0 = (tb & 63) * 128;

  const int qq = lane >> 4;             // 0..3
  const int r0 = lane & 15;

  // packed A base for this batch
  const unsigned short* xpan = xb + (size_t)b * 16 * XROWS * 32;
  const unsigned short* wpc  = wp;      // already offset per conv by caller

  f32x4 acc[4][8] = {};

  // stage A bucket cb into slot buf: 144 rows x 32ci, linear dest,
  // source ci-chunk pre-swizzled with (row&3) (read side applies same XOR).
  auto stA = [&](int cb, int buf) {
    const unsigned short* base =
        xpan + ((size_t)cb * XROWS + GUARD_B + t0 - 5) * 32;
    const int rr = lane >> 2;                       // row within 16-group
    const int sc = (lane & 3) ^ (rr & 3);           // inverse-swizzled chunk
    {
      const int i = wid;
      gload16(base + (size_t)(i * 16 + rr) * 32 + sc * 8,
              &Abuf[buf][i * 512]);
    }
    if (wid == 0) {
      const int i = 8;
      gload16(base + (size_t)(i * 16 + rr) * 32 + sc * 8,
              &Abuf[buf][i * 512]);
    }
  };
  // stage B step s (32 chunks x 1KB): fully contiguous source
  auto stB = [&](int s, int buf) {
    #pragma unroll
    for (int u = 0; u < 4; ++u) {
      const int chunk = u * 8 + wid;
      gload16(wpc + ((size_t)s * 32 + chunk) * 512 + lane * 8,
              &Bbuf[buf][chunk * 512]);
    }
  };

  // prologue
  stA(0, 0);
  stB(0, 0);
  __syncthreads();                 // implicit vmcnt(0) drain

  for (int cb = 0; cb < 16; ++cb) {
    const int abuf = cb & 1;
    #pragma unroll
    for (int tap = 0; tap < 3; ++tap) {
      const int s = cb * 3 + tap;
      // issue next stages BEFORE compute (fly under MFMA + ds_reads)
      if (s < 47) stB(s + 1, (s + 1) & 1);
      if (tap == 2 && cb < 15) stA(cb + 1, (cb + 1) & 1);

      // B frags: 8 col-tiles for this wave
      short8 bf[8];
      #pragma unroll
      for (int j = 0; j < 8; ++j)
        bf[j] = *reinterpret_cast<const short8*>(
            &Bbuf[s & 1][(wn * 8 + j) * 512 + lane * 8]);
      // A frags: 4 row-tiles (halo base 5, tap shift)
      short8 af[4];
      const int rbase = 5 + (tap - 1) * DIL + wm * 64;
      #pragma unroll
      for (int rt = 0; rt < 4; ++rt) {
        const int row = rbase + rt * 16 + r0;
        af[rt] = *reinterpret_cast<const short8*>(
            &Abuf[abuf][row * 32 + (qq ^ (row & 3)) * 8]);
      }
      __builtin_amdgcn_s_setprio(1);
      #pragma unroll
      for (int rt = 0; rt < 4; ++rt)
        #pragma unroll
        for (int j = 0; j < 8; ++j)
          acc[rt][j] = MFMA16(af[rt], bf[j], acc[rt][j]);
      __builtin_amdgcn_s_setprio(0);

      __syncthreads();             // drains: next buffers ready
    }
  }

  // epilogue: D row = qq*4 + e, col = lane&15
  #pragma unroll
  for (int j = 0; j < 8; ++j) {
    const int co = wn * 128 + j * 16 + r0;
    const float bv = bia[co];
    #pragma unroll
    for (int rt = 0; rt < 4; ++rt) {
      const int t = t0 + wm * 64 + rt * 16 + qq * 4;
      #pragma unroll
      for (int e = 0; e < 4; ++e) {
        const size_t off = ((size_t)b * TLEN + t + e) * CCH + co;
        float o = acc[rt][j][e] + bv;
        if constexpr (MODE == 1) o += resf[off];
        if constexpr (MODE == 2 || MODE == 3) o += bf2f(resb[off]);
        if constexpr (MODE == 3) outf[off] = o;
        else                     outb[off] = f2bf(o);
      }
    }
  }
}

// ---------------------------------------------------------------------------
// host: kaiser-sinc filter (double precision, matches numpy)
// ---------------------------------------------------------------------------
static double bessel_i0(double x) {
  double t = 1.0, s = 1.0, q = x * x * 0.25;
  for (int k = 1; k < 64; ++k) {
    t *= q / ((double)k * (double)k);
    s += t;
    if (t < 1e-18 * s) break;
  }
  return s;
}

static void make_filter(Filt* F) {
  const double cutoff = 0.25, hw = 0.3;
  const int ks = 12, half = 6;
  const double A = 2.285 * (half - 1) * M_PI * (4.0 * hw) + 7.95;
  double beta;
  if (A > 50.0)       beta = 0.1102 * (A - 8.7);
  else if (A >= 21.0) beta = 0.5842 * pow(A - 21.0, 0.4) + 0.07886 * (A - 21.0);
  else                beta = 0.0;
  const double i0b = bessel_i0(beta);
  double f[12], sum = 0.0;
  for (int n = 0; n < 12; ++n) {
    double rr = 2.0 * n / (ks - 1) - 1.0;
    double w  = bessel_i0(beta * sqrt(fmax(0.0, 1.0 - rr * rr))) / i0b;
    double tm = (double)(n - half) + 0.5;
    double sx = 2.0 * cutoff * tm;
    double snc = (sx == 0.0) ? 1.0 : sin(M_PI * sx) / (M_PI * sx);
    f[n] = 2.0 * cutoff * w * snc;
    sum += f[n];
  }
  for (int n = 0; n < 12; ++n) F->f[n] = (float)(f[n] / sum);
}

// ---------------------------------------------------------------------------
extern "C" void kernel_launch(void* const* d_in, const int* in_sizes, int n_in,
                              void* d_out, int out_size, void* d_ws, size_t ws_size,
                              hipStream_t stream) {
  (void)in_sizes; (void)n_in; (void)out_size; (void)ws_size;
  const float* x  = (const float*)d_in[0];
  const float* v1 = (const float*)d_in[1];
  const float* g1 = (const float*)d_in[2];
  const float* b1 = (const float*)d_in[3];
  const float* v2 = (const float*)d_in[4];
  const float* g2 = (const float*)d_in[5];
  const float* b2 = (const float*)d_in[6];
  const float* al = (const float*)d_in[7];
  float* out = (float*)d_out;

  const size_t N = (size_t)NBATCH * TLEN * CCH;
  // ws: [wb1 bf16: N][xbuf bf16 packed][xres bf16: N][wp packed][part][scl]
  unsigned short* wb1  = (unsigned short*)d_ws;
  unsigned short* xbuf = wb1 + N;
  unsigned short* xres = xbuf + (size_t)NBATCH * 16 * XROWS * 32;
  unsigned short* wp   = xres + N;
  float* part = (float*)(wp + (size_t)6 * 3 * CCH * CCH);
  float* scl  = part + (size_t)6 * CCH * 24;

  Filt F;
  make_filter(&F);

  zguard_k<<<96, 512, 0, stream>>>(xbuf);
  normp_k<<<dim3(6, 8, 24), 256, 0, stream>>>(v1, v2, part);
  fin_k<<<12, 256, 0, stream>>>(part, g1, g2, scl);
  wprep_k<<<2304, 256, 0, stream>>>(v1, v2, scl, wp);

  const int cgrid = NBATCH * (TLEN / 128);              // 256 blocks
  const int nblk_act = (NBATCH * 2048 * 128) / 256;     // 4096 blocks
  const size_t wsz = (size_t)3 * CCH * CCH;

  // iter 0: act1(x fp32) -> conv1<1> -> act2 -> conv2 (res x fp32, out xres bf16)
  act_k<0><<<nblk_act, 256, 0, stream>>>(x, xbuf, al + 0 * CCH, F);
  convm_k<1, 0><<<cgrid, 512, 0, stream>>>(xbuf, wp + 0 * wsz, b1 + 0 * CCH,
                                           nullptr, nullptr, nullptr, wb1);
  act_k<1><<<nblk_act, 256, 0, stream>>>(wb1, xbuf, al + 1 * CCH, F);
  convm_k<1, 1><<<cgrid, 512, 0, stream>>>(xbuf, wp + 3 * wsz, b2 + 0 * CCH,
                                           x, nullptr, nullptr, xres);

  // iter 1: act1(xres bf16) -> conv1<3> -> act2 -> conv2 (res/out xres bf16)
  act_k<1><<<nblk_act, 256, 0, stream>>>(xres, xbuf, al + 2 * CCH, F);
  convm_k<3, 0><<<cgrid, 512, 0, stream>>>(xbuf, wp + 1 * wsz, b1 + 1 * CCH,
                                           nullptr, nullptr, nullptr, wb1);
  act_k<1><<<nblk_act, 256, 0, stream>>>(wb1, xbuf, al + 3 * CCH, F);
  convm_k<1, 2><<<cgrid, 512, 0, stream>>>(xbuf, wp + 4 * wsz, b2 + 1 * CCH,
                                           nullptr, xres, nullptr, xres);

  // iter 2: act1(xres bf16) -> conv1<5> -> act2 -> conv2 (res xres, out fp32)
  act_k<1><<<nblk_act, 256, 0, stream>>>(xres, xbuf, al + 4 * CCH, F);
  convm_k<5, 0><<<cgrid, 512, 0, stream>>>(xbuf, wp + 2 * wsz, b1 + 2 * CCH,
                                           nullptr, nullptr, nullptr, wb1);
  act_k<1><<<nblk_act, 256, 0, stream>>>(wb1, xbuf, al + 5 * CCH, F);
  convm_k<1, 3><<<cgrid, 512, 0, stream>>>(xbuf, wp + 5 * wsz, b2 + 2 * CCH,
                                           nullptr, xres, out, nullptr);
}

// Round 17
// 647.462 us; speedup vs baseline: 1.1748x; 1.1748x over previous
//
#include <hip/hip_runtime.h>
#include <math.h>

// Problem constants (fixed by setup_inputs)
#define TLEN   8192
#define CCH    512
#define NBATCH 4
#define GUARD_B 8
#define GUARD_T 16
#define XROWS  (TLEN + GUARD_B + GUARD_T)   // 8216 guarded rows per batch

typedef __attribute__((ext_vector_type(8))) short short8;
typedef __attribute__((ext_vector_type(4))) float f32x4;

struct Filt { float f[12]; };

#define MFMA16(a, b, c) __builtin_amdgcn_mfma_f32_16x16x32_bf16(a, b, c, 0, 0, 0)
#define BARRIER() asm volatile("s_barrier" ::: "memory")
#define VMCNT(n)  asm volatile("s_waitcnt vmcnt(" #n ")" ::: "memory")

// ---------------------------------------------------------------------------
// device helpers
// ---------------------------------------------------------------------------
__device__ __forceinline__ unsigned short f2bf(float f) {
  unsigned u = __float_as_uint(f);
  unsigned r = (u + 0x7fffu + ((u >> 16) & 1u)) >> 16;   // RNE
  return (unsigned short)r;
}

__device__ __forceinline__ float bf2f(unsigned short u) {
  return __uint_as_float((unsigned)u << 16);
}

__device__ __forceinline__ float fast_sin(float x) {
  float r = x * 0.15915494309189535f;   // radians -> revolutions
  r -= floorf(r);
  return __builtin_amdgcn_sinf(r);
}

__device__ __forceinline__ float snake1(float u, float a, float rcp) {
  float s = fast_sin(a * u);
  return fmaf(rcp * s, s, u);   // u + (1/a)*sin^2(a*u)
}

// global (per-lane addr) -> LDS (wave-uniform base; HW adds lane*16), 16B/lane
__device__ __forceinline__ void gload16(const void* g, void* l) {
  __builtin_amdgcn_global_load_lds(
      (const __attribute__((address_space(1))) unsigned int*)g,
      (__attribute__((address_space(3))) unsigned int*)l, 16, 0, 0);
}

// ---------------------------------------------------------------------------
// weight-norm sum-of-squares, stage 1: partial[(c*512+co)*24 + jc]
// ---------------------------------------------------------------------------
__global__ __launch_bounds__(256)
void normp_k(const float* __restrict__ v1, const float* __restrict__ v2,
             float* __restrict__ part) {
  __shared__ float red[256];
  const int c  = blockIdx.x;
  const int cc = blockIdx.y;
  const int jc = blockIdx.z;
  const int col = threadIdx.x & 63;
  const int js  = threadIdx.x >> 6;
  const int co = cc * 64 + col;
  const float* v = (c < 3) ? v1 + (size_t)c * 3 * CCH * CCH
                           : v2 + (size_t)(c - 3) * 3 * CCH * CCH;
  const int j0 = jc * 64 + js * 16;
  float s = 0.f;
  #pragma unroll
  for (int jj = 0; jj < 16; ++jj) {
    float w = v[(size_t)(j0 + jj) * CCH + co];
    s = fmaf(w, w, s);
  }
  red[threadIdx.x] = s;
  __syncthreads();
  if (threadIdx.x < 64) {
    float t = red[threadIdx.x] + red[threadIdx.x + 64] +
              red[threadIdx.x + 128] + red[threadIdx.x + 192];
    part[(size_t)(c * CCH + co) * 24 + jc] = t;
  }
}

// stage 2: scl[c*512+co] = g / sqrt(sum of 24 partials)
__global__ __launch_bounds__(256)
void fin_k(const float* __restrict__ part, const float* __restrict__ g1,
           const float* __restrict__ g2, float* __restrict__ scl) {
  const int i = blockIdx.x * 256 + threadIdx.x;   // 0..3071
  const int c = i >> 9, co = i & 511;
  float s = 0.f;
  #pragma unroll
  for (int jc = 0; jc < 24; ++jc) s += part[(size_t)i * 24 + jc];
  const float g = (c < 3) ? g1[c * CCH + co] : g2[(c - 3) * CCH + co];
  scl[i] = g / sqrtf(s);
}

// ---------------------------------------------------------------------------
// zero the guard rows of the bf16 activation buffer (24 rows per batch)
// ---------------------------------------------------------------------------
__global__ __launch_bounds__(512)
void zguard_k(unsigned short* __restrict__ xb) {
  const int b = blockIdx.x / 24;
  const int g = blockIdx.x % 24;
  const int row = (g < 8) ? g : (TLEN + g);          // 0..7 and 8200..8215
  xb[((size_t)b * XROWS + row) * CCH + threadIdx.x] = 0;
}

// ---------------------------------------------------------------------------
// pack weights into MFMA B-fragment order (weight-norm scale folded in).
// Layout: wp[c][s=cib*3+tap][coT(2)][half(2)][chunk(16)][512]
//   co = coT*256 + half*128 + nf*16 + (lane&15),  chunk = nf*2+kk
//   ci = cib*64 + kk*32 + (lane>>4)*8 + j
// ---------------------------------------------------------------------------
__global__ __launch_bounds__(256)
void wprep_k(const float* __restrict__ v1, const float* __restrict__ v2,
             const float* __restrict__ scl, unsigned short* __restrict__ wp) {
  const int gtid = blockIdx.x * 256 + threadIdx.x;
  const int lane = gtid & 63;
  const int gw = gtid >> 6;            // 0..9215
  const int c  = gw / 1536;
  const int r  = gw - c * 1536;
  const int s  = r >> 6;               // 0..23
  const int r2 = r & 63;
  const int coT  = r2 >> 5;
  const int half = (r2 >> 4) & 1;
  const int cb   = r2 & 15;
  const int tap = s % 3, cib = s / 3;
  const int nf = cb >> 1, kk = cb & 1;
  const int co  = coT * 256 + half * 128 + nf * 16 + (lane & 15);
  const int ci0 = cib * 64 + kk * 32 + (lane >> 4) * 8;
  const float* v = (c < 3) ? v1 + (size_t)c * 3 * CCH * CCH
                           : v2 + (size_t)(c - 3) * 3 * CCH * CCH;
  const float sc = scl[c * CCH + co];
  unsigned short o[8];
  #pragma unroll
  for (int j = 0; j < 8; ++j) {
    float w = v[((size_t)tap * CCH + ci0 + j) * CCH + co] * sc;
    o[j] = f2bf(w);
  }
  *reinterpret_cast<short8*>(wp + (size_t)gw * 512 + lane * 8) =
      *reinterpret_cast<const short8*>(o);
}

// ---------------------------------------------------------------------------
// fused Activation1d: 2x upsample -> snake -> 2x downsample, strip-tiled.
// INBF: input is bf16 (flat B,T,C), else fp32.
// ---------------------------------------------------------------------------
template<int INBF>
__global__ __launch_bounds__(256)
void act_k(const void* __restrict__ xin, unsigned short* __restrict__ y,
           const float* __restrict__ la, Filt F) {
  const int idx = blockIdx.x * 256 + threadIdx.x;    // 4 * 2048 * 128 threads
  const int c  = (idx & 127) << 2;
  const int ts = (idx >> 7) & 2047;                  // strip index (t0 = 4*ts)
  const int b  = idx >> 18;
  const int t0 = ts * 4;

  auto ldrow = [&](int row) -> f32x4 {
    if constexpr (INBF) {
      const unsigned short* p =
          (const unsigned short*)xin + ((size_t)b * TLEN + row) * CCH + c;
      ushort4 u = *reinterpret_cast<const ushort4*>(p);
      f32x4 r;
      r[0] = bf2f(u.x); r[1] = bf2f(u.y); r[2] = bf2f(u.z); r[3] = bf2f(u.w);
      return r;
    } else {
      const float* p = (const float*)xin + ((size_t)b * TLEN + row) * CCH + c;
      return *reinterpret_cast<const f32x4*>(p);
    }
  };

  float av[4], rv[4];
  #pragma unroll
  for (int ch = 0; ch < 4; ++ch) {
    av[ch] = expf(la[c + ch]);
    rv[ch] = 1.f / (av[ch] + 1e-9f);
  }

  float acc[4][4];   // [tt][ch]

  if (ts >= 2 && ts <= 2045) {
    f32x4 xw[14];
    #pragma unroll
    for (int j = 0; j < 14; ++j) xw[j] = ldrow(t0 - 5 + j);

    #pragma unroll
    for (int ch = 0; ch < 4; ++ch) {
      float s[18];
      #pragma unroll
      for (int mi = 0; mi < 18; ++mi) {
        float u = 0.f;
        if (mi & 1) {
          const int base = (mi - 5) / 2 + 2;
          #pragma unroll
          for (int r = 0; r < 6; ++r) u = fmaf(F.f[2*r], xw[base + r][ch], u);
        } else {
          const int base = (mi - 6) / 2 + 3;
          #pragma unroll
          for (int r = 0; r < 6; ++r) u = fmaf(F.f[2*r+1], xw[base + r][ch], u);
        }
        u *= 2.f;
        s[mi] = snake1(u, av[ch], rv[ch]);
      }
      #pragma unroll
      for (int tt = 0; tt < 4; ++tt) {
        float a = 0.f;
        #pragma unroll
        for (int k = 0; k < 12; ++k) a = fmaf(F.f[k], s[2*tt + k], a);
        acc[tt][ch] = a;
      }
    }
  } else {
    #pragma unroll
    for (int tt = 0; tt < 4; ++tt) {
      const int t = t0 + tt;
      float a0=0.f, a1=0.f, a2=0.f, a3=0.f;
      for (int k = 0; k < 12; ++k) {
        int m  = 2*t + k - 5;
        int mc = m < 0 ? 0 : (m > 2*TLEN - 1 ? 2*TLEN - 1 : m);
        int tp = mc >> 1;
        int odd = mc & 1;
        float u0=0.f,u1=0.f,u2=0.f,u3=0.f;
        #pragma unroll
        for (int r = 0; r < 6; ++r) {
          int i  = odd ? (tp + r - 2) : (tp + r - 3);
          int ic = i < 0 ? 0 : (i > TLEN - 1 ? TLEN - 1 : i);
          float tap = odd ? F.f[2*r+1] : F.f[2*r];
          f32x4 xv = ldrow(ic);
          u0 = fmaf(tap, xv[0], u0); u1 = fmaf(tap, xv[1], u1);
          u2 = fmaf(tap, xv[2], u2); u3 = fmaf(tap, xv[3], u3);
        }
        u0 *= 2.f; u1 *= 2.f; u2 *= 2.f; u3 *= 2.f;
        const float fk = F.f[k];
        a0 = fmaf(fk, snake1(u0,av[0],rv[0]), a0);
        a1 = fmaf(fk, snake1(u1,av[1],rv[1]), a1);
        a2 = fmaf(fk, snake1(u2,av[2],rv[2]), a2);
        a3 = fmaf(fk, snake1(u3,av[3],rv[3]), a3);
      }
      acc[tt][0]=a0; acc[tt][1]=a1; acc[tt][2]=a2; acc[tt][3]=a3;
    }
  }

  #pragma unroll
  for (int tt = 0; tt < 4; ++tt) {
    ushort4 o;
    o.x = f2bf(acc[tt][0]); o.y = f2bf(acc[tt][1]);
    o.z = f2bf(acc[tt][2]); o.w = f2bf(acc[tt][3]);
    *reinterpret_cast<ushort4*>(
        y + ((size_t)b * XROWS + GUARD_B + t0 + tt) * CCH + c) = o;
  }
}

// ---------------------------------------------------------------------------
// MFMA conv — deep-lead 12-phase schedule (session-best: 648.5us total).
// im2col GEMM M=32768, N=512, K=24 steps of 64; group = 3 steps (one cib).
// 256x256 tile, 8 waves (2M x 4N), per-wave 128x64 out.
// A: 2 slots x [272 rows x 64 ci] (68KB), staged ONCE per cib (covers all 3
//    taps via halo), 5 instr at ph5-9, consumed next group (lead 3-7 ph).
// B: ring of 5 x 16KB half-tiles (80KB). B_{T+2} staged ph1-4, B_{T+3}
//    ph5-8, B_{T+4} ph9-12 (leads 4-8 phases, FIFO-consistent).
// Drains: vmcnt(4) @ph4, vmcnt(8) @ph8, vmcnt(4) @ph12 (FIFO-sim verified).
// MODE: 0 = conv1 (bf16 out); 1 = conv2 res fp32 -> bf16; 2 = res bf16 ->
//       bf16; 3 = res bf16 -> fp32 (final).
// ---------------------------------------------------------------------------
template<int DIL, int MODE>
__global__ __launch_bounds__(512, 2)
void convm_k(const unsigned short* __restrict__ xb,
             const unsigned short* __restrict__ wp,
             const float* __restrict__ bia,
             const float* __restrict__ resf,
             const unsigned short* __restrict__ resb,
             float* __restrict__ outf,
             unsigned short* __restrict__ outb) {
  __shared__ unsigned short Abuf[2][272 * 64];   // 68KB
  __shared__ unsigned short Bbuf[5][16 * 512];   // 80KB

  const int tid  = threadIdx.x;
  const int lane = tid & 63;
  const int wid  = tid >> 6;            // 0..7
  const int wr   = wid >> 2;            // 0..1  M half (rows wr*128..+127)
  const int wcn  = wid & 3;             // 0..3  N quarter (co wcn*64..+63)
  const int hb   = wcn >> 1;            // B half this wave reads

  // XCD-bijective swizzle: 256 blocks, 32 per XCD; 2 coT of a t-panel adjacent
  const int l   = (blockIdx.x & 7) * 32 + (blockIdx.x >> 3);
  const int coT = l & 1;
  const int tb  = l >> 1;               // 0..127
  const int b   = tb >> 5;
  const int t0  = (tb & 31) * 256;
  const int co0 = coT * 256;

  const int qq = lane >> 4;             // 0..3
  const int r0 = lane & 15;

  const int a_r = lane >> 3;            // staging: row within 8-row group
  const int a_c = (lane & 7) ^ a_r;     // inverse-swizzled ci chunk

  // A slot row 0 = abs row t0-8 (GUARD_B=8 covers all DIL<=5)
  const unsigned short* xrow0 =
      xb + ((size_t)b * XROWS + GUARD_B + t0 - 8) * CCH;
  const unsigned short* wpc = wp;       // already offset per conv by caller

  f32x4 acc[8][4] = {};
  short8 bfr[4][2];                     // B frags for current step

  // ---- staging ----
  auto stA = [&](int cib, int i) {      // i = 0..4; one VMEM instr per thread
    int G;
    if (i < 4) G = i * 8 + wid;                       // rows 0..255
    else       G = (wid >= 6) ? (26 + wid) : wid;     // wid6->G32, wid7->G33
    const unsigned short* g =
        xrow0 + (size_t)(8 * G + a_r) * CCH + cib * 64 + a_c * 8;
    gload16(g, &Abuf[cib & 1][G * 512]);
  };
  auto stB = [&](int s, int i) {        // i = 0..3 (half=i>>1, part=i&1)
    const int half = i >> 1, part = i & 1;
    const int pos = (2 * s + half) % 5;
    const unsigned short* g =
        wpc + ((((size_t)s * 2 + coT) * 2 + half) * 16 + part * 8) * 512 + tid * 8;
    gload16(g, &Bbuf[pos][part * 4096 + wid * 512]);
  };
  // ---- LDS -> regs ----
  auto ldB = [&](int s) {
    const int pos = (2 * s + hb) % 5;
    #pragma unroll
    for (int j = 0; j < 4; ++j)
      #pragma unroll
      for (int kk = 0; kk < 2; ++kk) {
        const int chunk = ((wcn & 1) * 4 + j) * 2 + kk;
        bfr[j][kk] = *reinterpret_cast<const short8*>(
            &Bbuf[pos][chunk * 512 + lane * 8]);
      }
  };
  auto ldA = [&](int pa, int tap, int q, short8 (&af)[2][2]) {
    const int tapoff = 8 + (tap - 1) * DIL;
    const int xr = (tapoff + r0) & 7;
    #pragma unroll
    for (int e = 0; e < 2; ++e) {
      const int row = tapoff + wr * 128 + q * 32 + e * 16 + r0;
      #pragma unroll
      for (int kk = 0; kk < 2; ++kk)
        af[e][kk] = *reinterpret_cast<const short8*>(
            &Abuf[pa][row * 64 + ((kk * 4 + qq) ^ xr) * 8]);
    }
  };
  auto mma = [&](int q, short8 (&af)[2][2]) {
    __builtin_amdgcn_s_setprio(1);
    #pragma unroll
    for (int kk = 0; kk < 2; ++kk)
      #pragma unroll
      for (int e = 0; e < 2; ++e)
        #pragma unroll
        for (int j = 0; j < 4; ++j)
          acc[q * 2 + e][j] = MFMA16(af[e][kk], bfr[j][kk], acc[q * 2 + e][j]);
    __builtin_amdgcn_s_setprio(0);
  };

  // prologue: [A_0, B_0] interleaved, then B_1  (13 instr); keep B_1 in flight
  stA(0, 0); stB(0, 0); stA(0, 1); stB(0, 1);
  stA(0, 2); stB(0, 2); stA(0, 3); stB(0, 3); stA(0, 4);
  stB(1, 0); stB(1, 1); stB(1, 2); stB(1, 3);
  VMCNT(4);
  BARRIER();

  for (int c = 0; c < 8; ++c) {
    const int T = 3 * c;
    const int pa = c & 1;
    short8 af[2][2];
    const bool more = (c < 7);

    // ---- step T (ph1-4): stage B_{T+2} ----
    ldB(T);
    ldA(pa, 0, 0, af); stB(T + 2, 0);
    BARRIER(); mma(0, af); BARRIER();
    ldA(pa, 0, 1, af); stB(T + 2, 1);
    BARRIER(); mma(1, af); BARRIER();
    ldA(pa, 0, 2, af); stB(T + 2, 2);
    BARRIER(); mma(2, af); BARRIER();
    ldA(pa, 0, 3, af); stB(T + 2, 3);
    VMCNT(4);                            // need B_{T+1}; keep B_{T+2}
    BARRIER(); mma(3, af); BARRIER();

    // ---- step T+1 (ph5-8): stage B_{T+3} + A_{c+1} (if more) ----
    ldB(T + 1);
    ldA(pa, 1, 0, af); if (more) { stB(T + 3, 0); stA(c + 1, 0); }
    BARRIER(); mma(0, af); BARRIER();
    ldA(pa, 1, 1, af); if (more) { stB(T + 3, 1); stA(c + 1, 1); }
    BARRIER(); mma(1, af); BARRIER();
    ldA(pa, 1, 2, af); if (more) { stB(T + 3, 2); stA(c + 1, 2); }
    BARRIER(); mma(2, af); BARRIER();
    ldA(pa, 1, 3, af); if (more) { stB(T + 3, 3); stA(c + 1, 3); }
    if (more) { VMCNT(8); } else { VMCNT(0); }   // need B_{T+2}
    BARRIER(); mma(3, af); BARRIER();

    // ---- step T+2 (ph9-12): stage A5 + B_{T+4} (if more) ----
    ldB(T + 2);
    ldA(pa, 2, 0, af); if (more) { stA(c + 1, 4); stB(T + 4, 0); }
    BARRIER(); mma(0, af); BARRIER();
    ldA(pa, 2, 1, af); if (more) stB(T + 4, 1);
    BARRIER(); mma(1, af); BARRIER();
    ldA(pa, 2, 2, af); if (more) stB(T + 4, 2);
    BARRIER(); mma(2, af); BARRIER();
    ldA(pa, 2, 3, af);
    if (more) { stB(T + 4, 3); VMCNT(4); }       // need A_{c+1}+B_{T+3}
    BARRIER(); mma(3, af); BARRIER();
  }

  // epilogue: D row = qq*4 + e, col = lane&15
  #pragma unroll
  for (int j = 0; j < 4; ++j) {
    const int co = co0 + wcn * 64 + j * 16 + r0;
    const float bv = bia[co];
    #pragma unroll
    for (int i = 0; i < 8; ++i) {
      const int t = t0 + wr * 128 + i * 16 + qq * 4;
      #pragma unroll
      for (int e = 0; e < 4; ++e) {
        const size_t off = ((size_t)b * TLEN + t + e) * CCH + co;
        float o = acc[i][j][e] + bv;
        if constexpr (MODE == 1) o += resf[off];
        if constexpr (MODE == 2 || MODE == 3) o += bf2f(resb[off]);
        if constexpr (MODE == 3) outf[off] = o;
        else                     outb[off] = f2bf(o);
      }
    }
  }
}

// ---------------------------------------------------------------------------
// host: kaiser-sinc filter (double precision, matches numpy)
// ---------------------------------------------------------------------------
static double bessel_i0(double x) {
  double t = 1.0, s = 1.0, q = x * x * 0.25;
  for (int k = 1; k < 64; ++k) {
    t *= q / ((double)k * (double)k);
    s += t;
    if (t < 1e-18 * s) break;
  }
  return s;
}

static void make_filter(Filt* F) {
  const double cutoff = 0.25, hw = 0.3;
  const int ks = 12, half = 6;
  const double A = 2.285 * (half - 1) * M_PI * (4.0 * hw) + 7.95;
  double beta;
  if (A > 50.0)       beta = 0.1102 * (A - 8.7);
  else if (A >= 21.0) beta = 0.5842 * pow(A - 21.0, 0.4) + 0.07886 * (A - 21.0);
  else                beta = 0.0;
  const double i0b = bessel_i0(beta);
  double f[12], sum = 0.0;
  for (int n = 0; n < 12; ++n) {
    double rr = 2.0 * n / (ks - 1) - 1.0;
    double w  = bessel_i0(beta * sqrt(fmax(0.0, 1.0 - rr * rr))) / i0b;
    double tm = (double)(n - half) + 0.5;
    double sx = 2.0 * cutoff * tm;
    double snc = (sx == 0.0) ? 1.0 : sin(M_PI * sx) / (M_PI * sx);
    f[n] = 2.0 * cutoff * w * snc;
    sum += f[n];
  }
  for (int n = 0; n < 12; ++n) F->f[n] = (float)(f[n] / sum);
}

// ---------------------------------------------------------------------------
extern "C" void kernel_launch(void* const* d_in, const int* in_sizes, int n_in,
                              void* d_out, int out_size, void* d_ws, size_t ws_size,
                              hipStream_t stream) {
  (void)in_sizes; (void)n_in; (void)out_size; (void)ws_size;
  const float* x  = (const float*)d_in[0];
  const float* v1 = (const float*)d_in[1];
  const float* g1 = (const float*)d_in[2];
  const float* b1 = (const float*)d_in[3];
  const float* v2 = (const float*)d_in[4];
  const float* g2 = (const float*)d_in[5];
  const float* b2 = (const float*)d_in[6];
  const float* al = (const float*)d_in[7];
  float* out = (float*)d_out;

  const size_t N = (size_t)NBATCH * TLEN * CCH;
  // ws: [wb1 bf16: N][xbuf bf16 guarded][xres bf16: N][wp packed][part][scl]
  unsigned short* wb1  = (unsigned short*)d_ws;
  unsigned short* xbuf = wb1 + N;
  unsigned short* xres = xbuf + (size_t)NBATCH * XROWS * CCH;
  unsigned short* wp   = xres + N;
  float* part = (float*)(wp + (size_t)6 * 3 * CCH * CCH);
  float* scl  = part + (size_t)6 * CCH * 24;

  Filt F;
  make_filter(&F);

  zguard_k<<<96, 512, 0, stream>>>(xbuf);
  normp_k<<<dim3(6, 8, 24), 256, 0, stream>>>(v1, v2, part);
  fin_k<<<12, 256, 0, stream>>>(part, g1, g2, scl);
  wprep_k<<<2304, 256, 0, stream>>>(v1, v2, scl, wp);

  const int cgrid = NBATCH * (TLEN / 256) * 2;          // 256 blocks
  const int nblk_act = (NBATCH * 2048 * 128) / 256;     // 4096 blocks
  const size_t wsz = (size_t)3 * CCH * CCH;

  // iter 0: act1(x fp32) -> conv1<1> -> act2 -> conv2 (res x fp32, out xres bf16)
  act_k<0><<<nblk_act, 256, 0, stream>>>(x, xbuf, al + 0 * CCH, F);
  convm_k<1, 0><<<cgrid, 512, 0, stream>>>(xbuf, wp + 0 * wsz, b1 + 0 * CCH,
                                           nullptr, nullptr, nullptr, wb1);
  act_k<1><<<nblk_act, 256, 0, stream>>>(wb1, xbuf, al + 1 * CCH, F);
  convm_k<1, 1><<<cgrid, 512, 0, stream>>>(xbuf, wp + 3 * wsz, b2 + 0 * CCH,
                                           x, nullptr, nullptr, xres);

  // iter 1: act1(xres bf16) -> conv1<3> -> act2 -> conv2 (res/out xres bf16)
  act_k<1><<<nblk_act, 256, 0, stream>>>(xres, xbuf, al + 2 * CCH, F);
  convm_k<3, 0><<<cgrid, 512, 0, stream>>>(xbuf, wp + 1 * wsz, b1 + 1 * CCH,
                                           nullptr, nullptr, nullptr, wb1);
  act_k<1><<<nblk_act, 256, 0, stream>>>(wb1, xbuf, al + 3 * CCH, F);
  convm_k<1, 2><<<cgrid, 512, 0, stream>>>(xbuf, wp + 4 * wsz, b2 + 1 * CCH,
                                           nullptr, xres, nullptr, xres);

  // iter 2: act1(xres bf16) -> conv1<5> -> act2 -> conv2 (res xres, out fp32)
  act_k<1><<<nblk_act, 256, 0, stream>>>(xres, xbuf, al + 4 * CCH, F);
  convm_k<5, 0><<<cgrid, 512, 0, stream>>>(xbuf, wp + 2 * wsz, b1 + 2 * CCH,
                                           nullptr, nullptr, nullptr, wb1);
  act_k<1><<<nblk_act, 256, 0, stream>>>(wb1, xbuf, al + 5 * CCH, F);
  convm_k<1, 3><<<cgrid, 512, 0, stream>>>(xbuf, wp + 5 * wsz, b2 + 2 * CCH,
                                           nullptr, xres, out, nullptr);
}